// Round 4
// baseline (369.125 us; speedup 1.0000x reference)
//
#include <hip/hip_runtime.h>
#include <math.h>

#define TPB 512
#define FPSCALE 262144.0f          // 2^18 fixed-point for fx/fy LDS accumulation
#define INV_FPSCALE (1.0f / 262144.0f)

// ctrl (floats) layout: [0:64) bn1 sum, [64:128) bn1 sumsq,
//                       [128:160) bn2 sum, [160:192) bn2 sumsq,
//                       ints at [192..195): grid-barrier counters (memset to 0)

__device__ __forceinline__ void grid_barrier(int* cnt, int nblk) {
    __syncthreads();
    __threadfence();                       // release this block's writes to device scope
    if (threadIdx.x == 0) {
        atomicAdd(cnt, 1);
        while (__hip_atomic_load(cnt, __ATOMIC_ACQUIRE, __HIP_MEMORY_SCOPE_AGENT) < nblk) { }
    }
    __syncthreads();
    __threadfence();                       // acquire remote writes for all threads
}

__global__ __launch_bounds__(TPB, 2)
void fused_all(const int* __restrict__ labels,
               const float* __restrict__ fx,
               const float* __restrict__ fy,
               const int* __restrict__ frame_idx,
               const int* __restrict__ n_frames_p,
               const float* __restrict__ conv_w,
               const float* __restrict__ conv_b,
               const float* __restrict__ bn1_g,
               const float* __restrict__ bn1_b,
               const float* __restrict__ lin_w,
               const float* __restrict__ lin_b,
               const float* __restrict__ bn2_g,
               const float* __restrict__ bn2_b,
               float* __restrict__ out,
               float* __restrict__ ctrl,
               float* __restrict__ partial,
               int K, int H, int W, int wlog, int chunks, int N) {
    __shared__ unsigned long long geo[1024];          // per-bin (sum_i<<40 | sum_j<<16 | count)
    __shared__ int   fxb[1024], fyb[1024];
    __shared__ float h1t[64 * 64];                    // [c][tt]
    __shared__ float h2t[32 * 65];                    // [o][tt], padded
    __shared__ float cw[320], cb[64];
    __shared__ float w2[2048], lb[32];
    __shared__ float red[320], feat[320];
    __shared__ float sc1[64], sh1[64], sc2[32], sh2[32];
    __shared__ float ssqp[8 * 64], linv[64];

    const int tid = threadIdx.x;
    int* cnt = (int*)(ctrl + 192);
    const int nblk = gridDim.x;

    // stage weights (overlaps pool phase)
    if (tid < 320) cw[tid] = conv_w[tid];
    if (tid < 64)  cb[tid] = conv_b[tid];
    for (int i = tid; i < 2048; i += TPB) w2[i] = lin_w[i];
    if (tid < 32)  lb[tid] = lin_b[tid];

    // ---------------- phase 1: pool into LDS int bins ----------------
    for (int i = tid; i < K; i += TPB) { geo[i] = 0ull; fxb[i] = 0; fyb[i] = 0; }
    __syncthreads();

    const int P = H * W;
    const int b = blockIdx.x / chunks;
    const int chunk = blockIdx.x - b * chunks;
    const int chunkP = P / chunks;
    const size_t base = (size_t)b * P + (size_t)chunk * chunkP;
    const int4*   l4p  = (const int4*)(labels + base);
    const float4* fx4p = (const float4*)(fx + base);
    const float4* fy4p = (const float4*)(fy + base);
    const int nvec = chunkP >> 2;

    for (int v = tid; v < nvec; v += TPB) {
        int4   l4 = l4p[v];
        float4 f4 = fx4p[v];
        float4 g4 = fy4p[v];
        int p0 = chunk * chunkP + (v << 2);
        int   ls[4] = {l4.x, l4.y, l4.z, l4.w};
        float fs[4] = {f4.x, f4.y, f4.z, f4.w};
        float gs[4] = {g4.x, g4.y, g4.z, g4.w};
        #pragma unroll
        for (int s = 0; s < 4; ++s) {
            int p = p0 + s;
            int i, j;
            if (wlog >= 0) { i = p >> wlog; j = p & (W - 1); }
            else           { i = p / W;     j = p - i * W; }
            unsigned long long gadd = ((unsigned long long)i << 40)
                                    | ((unsigned long long)j << 16) | 1ull;
            atomicAdd(&geo[ls[s]], gadd);
            atomicAdd(&fxb[ls[s]], __float2int_rn(fs[s] * FPSCALE));
            atomicAdd(&fyb[ls[s]], __float2int_rn(gs[s] * FPSCALE));
        }
    }
    __syncthreads();

    {
        const float sx = 2.f / (float)(H - 1);        // xx varies along dim 2 (i)
        const float sy = 2.f / (float)(W - 1);        // yy varies along dim 3 (j)
        float* outp = partial + (size_t)blockIdx.x * K * 5;
        for (int k = tid; k < K; k += TPB) {
            unsigned long long g = geo[k];
            float cnt_f = (float)(unsigned int)(g & 0xFFFFull);
            float sj    = (float)(unsigned int)((g >> 16) & 0xFFFFFFull);
            float si    = (float)(unsigned int)(g >> 40);
            float* p = outp + k * 5;
            p[0] = (float)fxb[k] * INV_FPSCALE;
            p[1] = (float)fyb[k] * INV_FPSCALE;
            p[2] = sx * si - cnt_f;
            p[3] = sy * sj - cnt_f;
            p[4] = cnt_f;
        }
    }

    grid_barrier(cnt + 0, nblk);

    // ---------------- phase 2: reduce slabs + mean + layer1 + bn1 stats ----------------
    const int t0 = blockIdx.x * 64;                   // 64 tokens per block, one batch each
    const int b2 = t0 / K;
    const int k0 = t0 - b2 * K;

    if (tid < 320) {
        float a = 0.f;
        const float* pb = partial + ((size_t)b2 * chunks * K + k0) * 5;
        for (int ch = 0; ch < chunks; ++ch)
            a += pb[(size_t)ch * K * 5 + tid];
        red[tid] = a;
    }
    __syncthreads();

    const int g  = tid >> 6;                          // 8 groups
    const int tt = tid & 63;
    if (tid < 64) {
        const float* r = red + tid * 5;
        float inv = 1.f / fmaxf(r[4], 1.f);
        float invnf = 1.f / (float)(n_frames_p[0] - 1);
        feat[tid * 5 + 0] = (float)frame_idx[b2] * invnf;
        feat[tid * 5 + 1] = r[0] * inv;
        feat[tid * 5 + 2] = r[1] * inv;
        feat[tid * 5 + 3] = r[2] * inv;
        feat[tid * 5 + 4] = r[3] * inv;
    }
    __syncthreads();

    const float x0 = feat[tt * 5 + 0], x1 = feat[tt * 5 + 1],
                x2 = feat[tt * 5 + 2], x3 = feat[tt * 5 + 3],
                x4 = feat[tt * 5 + 4];
    float hs[8];
    const int c0 = g * 8;
    #pragma unroll
    for (int j = 0; j < 8; ++j) {
        int c = c0 + j;
        const float* w = cw + c * 5;
        float h = cb[c] + w[0]*x0 + w[1]*x1 + w[2]*x2 + w[3]*x3 + w[4]*x4;
        hs[j] = h;
        h1t[c * 64 + tt] = h;
    }
    {
        float mySum = 0.f, mySq = 0.f;
        #pragma unroll
        for (int j = 0; j < 8; ++j) {
            float s = hs[j], q = hs[j] * hs[j];
            #pragma unroll
            for (int m = 1; m < 64; m <<= 1) {
                s += __shfl_xor(s, m, 64);
                q += __shfl_xor(q, m, 64);
            }
            if (tt == j) { mySum = s; mySq = q; }
        }
        if (tt < 8) {
            atomicAdd(ctrl + c0 + tt, mySum);
            atomicAdd(ctrl + 64 + c0 + tt, mySq);
        }
    }

    grid_barrier(cnt + 1, nblk);

    // ---------------- phase 3: fold bn1 + relu + layer2 + bn2 stats ----------------
    if (tid < 64) {
        float invN = 1.f / (float)N;
        float mean = ctrl[tid] * invN;
        float var  = ctrl[64 + tid] * invN - mean * mean;
        float s = bn1_g[tid] * rsqrtf(var + 1e-5f);
        sc1[tid] = s;
        sh1[tid] = bn1_b[tid] - mean * s;
    }
    __syncthreads();

    float y[64];
    #pragma unroll
    for (int c = 0; c < 64; ++c)
        y[c] = fmaxf(h1t[c * 64 + tt] * sc1[c] + sh1[c], 0.f);

    float h2s[4];
    const int o0 = g * 4;
    #pragma unroll
    for (int j = 0; j < 4; ++j) {
        int o = o0 + j;
        const float* wo = w2 + o * 64;
        float acc = lb[o];
        #pragma unroll
        for (int c = 0; c < 64; ++c) acc += wo[c] * y[c];
        h2s[j] = acc;
        h2t[o * 65 + tt] = acc;
    }
    {
        float mySum = 0.f, mySq = 0.f;
        #pragma unroll
        for (int j = 0; j < 4; ++j) {
            float s = h2s[j], q = h2s[j] * h2s[j];
            #pragma unroll
            for (int m = 1; m < 64; m <<= 1) {
                s += __shfl_xor(s, m, 64);
                q += __shfl_xor(q, m, 64);
            }
            if (tt == j) { mySum = s; mySq = q; }
        }
        if (tt < 4) {
            atomicAdd(ctrl + 128 + o0 + tt, mySum);
            atomicAdd(ctrl + 160 + o0 + tt, mySq);
        }
    }

    grid_barrier(cnt + 2, nblk);

    // ---------------- phase 4: fold bn2 + relu + L2 normalize + store ----------------
    if (tid < 32) {
        float invN = 1.f / (float)N;
        float mean = ctrl[128 + tid] * invN;
        float var  = ctrl[160 + tid] * invN - mean * mean;
        float s = bn2_g[tid] * rsqrtf(var + 1e-5f);
        sc2[tid] = s;
        sh2[tid] = bn2_b[tid] - mean * s;
    }
    __syncthreads();

    {
        float ss = 0.f;
        #pragma unroll
        for (int j = 0; j < 4; ++j) {
            int o = o0 + j;
            float v = fmaxf(h2t[o * 65 + tt] * sc2[o] + sh2[o], 0.f);
            h2t[o * 65 + tt] = v;
            ss += v * v;
        }
        ssqp[g * 64 + tt] = ss;
    }
    __syncthreads();
    if (tid < 64) {
        float tot = 0.f;
        #pragma unroll
        for (int q = 0; q < 8; ++q) tot += ssqp[q * 64 + tid];
        linv[tid] = 1.f / fmaxf(sqrtf(tot), 1e-8f);
    }
    __syncthreads();

    {
        const int tk = tid >> 3;
        const int oo = (tid & 7) * 4;
        float iv = linv[tk];
        float4 val = make_float4(h2t[(oo + 0) * 65 + tk] * iv,
                                 h2t[(oo + 1) * 65 + tk] * iv,
                                 h2t[(oo + 2) * 65 + tk] * iv,
                                 h2t[(oo + 3) * 65 + tk] * iv);
        ((float4*)out)[(size_t)blockIdx.x * TPB + tid] = val;
    }
}

extern "C" void kernel_launch(void* const* d_in, const int* in_sizes, int n_in,
                              void* d_out, int out_size, void* d_ws, size_t ws_size,
                              hipStream_t stream) {
    const int*   labels     = (const int*)d_in[0];
    const float* fx         = (const float*)d_in[1];
    const float* fy         = (const float*)d_in[2];
    const int*   frame_idx  = (const int*)d_in[3];
    const int*   n_frames_p = (const int*)d_in[4];
    // d_in[5] = n_labels (derived from out_size instead)
    const float* conv_w = (const float*)d_in[6];
    const float* conv_b = (const float*)d_in[7];
    const float* bn1_g  = (const float*)d_in[8];
    const float* bn1_b  = (const float*)d_in[9];
    const float* lin_w  = (const float*)d_in[10];
    const float* lin_b  = (const float*)d_in[11];
    const float* bn2_g  = (const float*)d_in[12];
    const float* bn2_b  = (const float*)d_in[13];
    float* out = (float*)d_out;

    const int B = in_sizes[3];                       // 16
    const int P = in_sizes[0] / B;                   // 262144
    const int W = (int)(sqrt((double)P) + 0.5);      // 512 (square image)
    const int H = P / W;
    const int K = out_size / (B * 32);               // 1024
    const int N = B * K;                             // 16384

    int wlog = -1;
    if ((W & (W - 1)) == 0) { wlog = 0; while ((1 << wlog) < W) ++wlog; }

    const int nblk   = N / 64;                       // 256 blocks = 1/CU, co-resident
    const int chunks = nblk / B;                     // 16 pool chunks per batch

    // workspace: ctrl[256 floats incl barrier counters] | partial[nblk*K*5]
    float* ctrl    = (float*)d_ws;
    float* partial = ctrl + 256;

    hipMemsetAsync(d_ws, 0, 1024, stream);           // zero stats + barrier counters
    fused_all<<<nblk, TPB, 0, stream>>>(
        labels, fx, fy, frame_idx, n_frames_p,
        conv_w, conv_b, bn1_g, bn1_b, lin_w, lin_b, bn2_g, bn2_b,
        out, ctrl, partial, K, H, W, wlog, chunks, N);
}

// Round 5
// 347.363 us; speedup vs baseline: 1.0626x; 1.0626x over previous
//
#include <hip/hip_runtime.h>
#include <math.h>

#define TPB 512
#define FPSCALE 262144.0f          // 2^18 fixed-point for fx/fy LDS accumulation
#define INV_FPSCALE (1.0f / 262144.0f)

// ctrl (floats) layout: [0:64) bn1 sum, [64:128) bn1 sumsq,
//                       [128:160) bn2 sum, [160:192) bn2 sumsq,
//                       ints at [192..195): grid-barrier counters (memset to 0)

__device__ __forceinline__ void grid_barrier(int* cnt, int nblk) {
    __syncthreads();
    __threadfence();                       // release: all threads drain their global writes
    if (threadIdx.x == 0) {
        atomicAdd(cnt, 1);
        // relaxed poll with sleep backoff: ~1k cycles between polls keeps the
        // counter cacheline free for arriving atomicAdds (round-4 tight spin
        // at acquire scope collapsed under 256-wave contention).
        while (__hip_atomic_load(cnt, __ATOMIC_RELAXED, __HIP_MEMORY_SCOPE_AGENT) < nblk)
            __builtin_amdgcn_s_sleep(16);
    }
    __syncthreads();
    __threadfence();                       // acquire: invalidate L1 so remote writes are seen
}

__global__ __launch_bounds__(TPB, 2)
void fused_all(const int* __restrict__ labels,
               const float* __restrict__ fx,
               const float* __restrict__ fy,
               const int* __restrict__ frame_idx,
               const int* __restrict__ n_frames_p,
               const float* __restrict__ conv_w,
               const float* __restrict__ conv_b,
               const float* __restrict__ bn1_g,
               const float* __restrict__ bn1_b,
               const float* __restrict__ lin_w,
               const float* __restrict__ lin_b,
               const float* __restrict__ bn2_g,
               const float* __restrict__ bn2_b,
               float* __restrict__ out,
               float* __restrict__ ctrl,
               float* __restrict__ partial,
               int K, int H, int W, int wlog, int chunks, int N) {
    __shared__ unsigned long long geo[1024];          // per-bin (sum_i<<40 | sum_j<<16 | count)
    __shared__ int   fxb[1024], fyb[1024];
    __shared__ float h1t[64 * 64];                    // [c][tt]
    __shared__ float h2t[32 * 65];                    // [o][tt], padded
    __shared__ float cw[320], cb[64];
    __shared__ float w2[2048], lb[32];
    __shared__ float red[320], feat[320];
    __shared__ float sc1[64], sh1[64], sc2[32], sh2[32];
    __shared__ float ssqp[8 * 64], linv[64];

    const int tid = threadIdx.x;
    int* cnt = (int*)(ctrl + 192);
    const int nblk = gridDim.x;

    // stage weights (overlaps pool phase)
    if (tid < 320) cw[tid] = conv_w[tid];
    if (tid < 64)  cb[tid] = conv_b[tid];
    for (int i = tid; i < 2048; i += TPB) w2[i] = lin_w[i];
    if (tid < 32)  lb[tid] = lin_b[tid];

    // ---------------- phase 1: pool into LDS int bins ----------------
    for (int i = tid; i < K; i += TPB) { geo[i] = 0ull; fxb[i] = 0; fyb[i] = 0; }
    __syncthreads();

    const int P = H * W;
    const int b = blockIdx.x / chunks;
    const int chunk = blockIdx.x - b * chunks;
    const int chunkP = P / chunks;
    const size_t base = (size_t)b * P + (size_t)chunk * chunkP;
    const int4*   l4p  = (const int4*)(labels + base);
    const float4* fx4p = (const float4*)(fx + base);
    const float4* fy4p = (const float4*)(fy + base);
    const int nvec = chunkP >> 2;

    for (int v = tid; v < nvec; v += TPB) {
        int4   l4 = l4p[v];
        float4 f4 = fx4p[v];
        float4 g4 = fy4p[v];
        int p0 = chunk * chunkP + (v << 2);
        int   ls[4] = {l4.x, l4.y, l4.z, l4.w};
        float fs[4] = {f4.x, f4.y, f4.z, f4.w};
        float gs[4] = {g4.x, g4.y, g4.z, g4.w};
        #pragma unroll
        for (int s = 0; s < 4; ++s) {
            int p = p0 + s;
            int i, j;
            if (wlog >= 0) { i = p >> wlog; j = p & (W - 1); }
            else           { i = p / W;     j = p - i * W; }
            unsigned long long gadd = ((unsigned long long)i << 40)
                                    | ((unsigned long long)j << 16) | 1ull;
            atomicAdd(&geo[ls[s]], gadd);
            atomicAdd(&fxb[ls[s]], __float2int_rn(fs[s] * FPSCALE));
            atomicAdd(&fyb[ls[s]], __float2int_rn(gs[s] * FPSCALE));
        }
    }
    __syncthreads();

    {
        const float sx = 2.f / (float)(H - 1);        // xx varies along dim 2 (i)
        const float sy = 2.f / (float)(W - 1);        // yy varies along dim 3 (j)
        float* outp = partial + (size_t)blockIdx.x * K * 5;
        for (int k = tid; k < K; k += TPB) {
            unsigned long long g = geo[k];
            float cnt_f = (float)(unsigned int)(g & 0xFFFFull);
            float sj    = (float)(unsigned int)((g >> 16) & 0xFFFFFFull);
            float si    = (float)(unsigned int)(g >> 40);
            float* p = outp + k * 5;
            p[0] = (float)fxb[k] * INV_FPSCALE;
            p[1] = (float)fyb[k] * INV_FPSCALE;
            p[2] = sx * si - cnt_f;
            p[3] = sy * sj - cnt_f;
            p[4] = cnt_f;
        }
    }

    grid_barrier(cnt + 0, nblk);

    // ---------------- phase 2: reduce slabs + mean + layer1 + bn1 stats ----------------
    const int t0 = blockIdx.x * 64;                   // 64 tokens per block, one batch each
    const int b2 = t0 / K;
    const int k0 = t0 - b2 * K;

    if (tid < 320) {
        float a = 0.f;
        const float* pb = partial + ((size_t)b2 * chunks * K + k0) * 5;
        for (int ch = 0; ch < chunks; ++ch)
            a += pb[(size_t)ch * K * 5 + tid];
        red[tid] = a;
    }
    __syncthreads();

    const int g  = tid >> 6;                          // 8 groups
    const int tt = tid & 63;
    if (tid < 64) {
        const float* r = red + tid * 5;
        float inv = 1.f / fmaxf(r[4], 1.f);
        float invnf = 1.f / (float)(n_frames_p[0] - 1);
        feat[tid * 5 + 0] = (float)frame_idx[b2] * invnf;
        feat[tid * 5 + 1] = r[0] * inv;
        feat[tid * 5 + 2] = r[1] * inv;
        feat[tid * 5 + 3] = r[2] * inv;
        feat[tid * 5 + 4] = r[3] * inv;
    }
    __syncthreads();

    const float x0 = feat[tt * 5 + 0], x1 = feat[tt * 5 + 1],
                x2 = feat[tt * 5 + 2], x3 = feat[tt * 5 + 3],
                x4 = feat[tt * 5 + 4];
    float hs[8];
    const int c0 = g * 8;
    #pragma unroll
    for (int j = 0; j < 8; ++j) {
        int c = c0 + j;
        const float* w = cw + c * 5;
        float h = cb[c] + w[0]*x0 + w[1]*x1 + w[2]*x2 + w[3]*x3 + w[4]*x4;
        hs[j] = h;
        h1t[c * 64 + tt] = h;
    }
    {
        float mySum = 0.f, mySq = 0.f;
        #pragma unroll
        for (int j = 0; j < 8; ++j) {
            float s = hs[j], q = hs[j] * hs[j];
            #pragma unroll
            for (int m = 1; m < 64; m <<= 1) {
                s += __shfl_xor(s, m, 64);
                q += __shfl_xor(q, m, 64);
            }
            if (tt == j) { mySum = s; mySq = q; }
        }
        if (tt < 8) {
            atomicAdd(ctrl + c0 + tt, mySum);
            atomicAdd(ctrl + 64 + c0 + tt, mySq);
        }
    }

    grid_barrier(cnt + 1, nblk);

    // ---------------- phase 3: fold bn1 + relu + layer2 + bn2 stats ----------------
    if (tid < 64) {
        float invN = 1.f / (float)N;
        float mean = ctrl[tid] * invN;
        float var  = ctrl[64 + tid] * invN - mean * mean;
        float s = bn1_g[tid] * rsqrtf(var + 1e-5f);
        sc1[tid] = s;
        sh1[tid] = bn1_b[tid] - mean * s;
    }
    __syncthreads();

    float y[64];
    #pragma unroll
    for (int c = 0; c < 64; ++c)
        y[c] = fmaxf(h1t[c * 64 + tt] * sc1[c] + sh1[c], 0.f);

    float h2s[4];
    const int o0 = g * 4;
    #pragma unroll
    for (int j = 0; j < 4; ++j) {
        int o = o0 + j;
        const float* wo = w2 + o * 64;
        float acc = lb[o];
        #pragma unroll
        for (int c = 0; c < 64; ++c) acc += wo[c] * y[c];
        h2s[j] = acc;
        h2t[o * 65 + tt] = acc;
    }
    {
        float mySum = 0.f, mySq = 0.f;
        #pragma unroll
        for (int j = 0; j < 4; ++j) {
            float s = h2s[j], q = h2s[j] * h2s[j];
            #pragma unroll
            for (int m = 1; m < 64; m <<= 1) {
                s += __shfl_xor(s, m, 64);
                q += __shfl_xor(q, m, 64);
            }
            if (tt == j) { mySum = s; mySq = q; }
        }
        if (tt < 4) {
            atomicAdd(ctrl + 128 + o0 + tt, mySum);
            atomicAdd(ctrl + 160 + o0 + tt, mySq);
        }
    }

    grid_barrier(cnt + 2, nblk);

    // ---------------- phase 4: fold bn2 + relu + L2 normalize + store ----------------
    if (tid < 32) {
        float invN = 1.f / (float)N;
        float mean = ctrl[128 + tid] * invN;
        float var  = ctrl[160 + tid] * invN - mean * mean;
        float s = bn2_g[tid] * rsqrtf(var + 1e-5f);
        sc2[tid] = s;
        sh2[tid] = bn2_b[tid] - mean * s;
    }
    __syncthreads();

    {
        float ss = 0.f;
        #pragma unroll
        for (int j = 0; j < 4; ++j) {
            int o = o0 + j;
            float v = fmaxf(h2t[o * 65 + tt] * sc2[o] + sh2[o], 0.f);
            h2t[o * 65 + tt] = v;
            ss += v * v;
        }
        ssqp[g * 64 + tt] = ss;
    }
    __syncthreads();
    if (tid < 64) {
        float tot = 0.f;
        #pragma unroll
        for (int q = 0; q < 8; ++q) tot += ssqp[q * 64 + tid];
        linv[tid] = 1.f / fmaxf(sqrtf(tot), 1e-8f);
    }
    __syncthreads();

    {
        const int tk = tid >> 3;
        const int oo = (tid & 7) * 4;
        float iv = linv[tk];
        float4 val = make_float4(h2t[(oo + 0) * 65 + tk] * iv,
                                 h2t[(oo + 1) * 65 + tk] * iv,
                                 h2t[(oo + 2) * 65 + tk] * iv,
                                 h2t[(oo + 3) * 65 + tk] * iv);
        ((float4*)out)[(size_t)blockIdx.x * TPB + tid] = val;
    }
}

extern "C" void kernel_launch(void* const* d_in, const int* in_sizes, int n_in,
                              void* d_out, int out_size, void* d_ws, size_t ws_size,
                              hipStream_t stream) {
    const int*   labels     = (const int*)d_in[0];
    const float* fx         = (const float*)d_in[1];
    const float* fy         = (const float*)d_in[2];
    const int*   frame_idx  = (const int*)d_in[3];
    const int*   n_frames_p = (const int*)d_in[4];
    // d_in[5] = n_labels (derived from out_size instead)
    const float* conv_w = (const float*)d_in[6];
    const float* conv_b = (const float*)d_in[7];
    const float* bn1_g  = (const float*)d_in[8];
    const float* bn1_b  = (const float*)d_in[9];
    const float* lin_w  = (const float*)d_in[10];
    const float* lin_b  = (const float*)d_in[11];
    const float* bn2_g  = (const float*)d_in[12];
    const float* bn2_b  = (const float*)d_in[13];
    float* out = (float*)d_out;

    const int B = in_sizes[3];                       // 16
    const int P = in_sizes[0] / B;                   // 262144
    const int W = (int)(sqrt((double)P) + 0.5);      // 512 (square image)
    const int H = P / W;
    const int K = out_size / (B * 32);               // 1024
    const int N = B * K;                             // 16384

    int wlog = -1;
    if ((W & (W - 1)) == 0) { wlog = 0; while ((1 << wlog) < W) ++wlog; }

    const int nblk   = N / 64;                       // 256 blocks = 1/CU, co-resident
    const int chunks = nblk / B;                     // 16 pool chunks per batch

    // workspace: ctrl[256 floats incl barrier counters] | partial[nblk*K*5]
    float* ctrl    = (float*)d_ws;
    float* partial = ctrl + 256;

    hipMemsetAsync(d_ws, 0, 1024, stream);           // zero stats + barrier counters
    fused_all<<<nblk, TPB, 0, stream>>>(
        labels, fx, fy, frame_idx, n_frames_p,
        conv_w, conv_b, bn1_g, bn1_b, lin_w, lin_b, bn2_g, bn2_b,
        out, ctrl, partial, K, H, W, wlog, chunks, N);
}

// Round 7
// 176.662 us; speedup vs baseline: 2.0894x; 1.9663x over previous
//
#include <hip/hip_runtime.h>
#include <math.h>

#define TPB 256
#define FSCALE 32768.0f            // 2^15 fixed-point for fx/fy
#define INV_FSCALE (1.0f / 32768.0f)
#define FBIAS (1 << 19)            // per-add bias keeps packed fields positive

// statsBuf layout (floats): [0:64) bn1 sum, [64:128) bn1 sumsq,
//                           [128:160) bn2 sum, [160:192) bn2 sumsq

// -------------------- segment pool: LDS int bins, 2 u64 atomics/pixel ------------
// geo packs (sum_i<<40 | sum_j<<16 | count). fxy packs biased fixed-point
// (fx*2^15 + 2^19)<<32 | (fy*2^15 + 2^19). chunkP<=4096 ensures
// worst-case field sums 4096*1015808 = 4.16e9 < 2^32 (no cross-field carry),
// count<=4096<2^16, sum_j<=4096*511<2^24. Flush converts to float[5] partials
// (identical format/consumers to the round-3 passing kernel chain).
__global__ void pool_kernel(const int* __restrict__ labels,
                            const float* __restrict__ fx,
                            const float* __restrict__ fy,
                            float* __restrict__ partial,
                            float* __restrict__ statsBuf,
                            int K, int H, int W, int wlog, int chunks) {
    extern __shared__ unsigned long long sh[];   // geo[K] | fxy[K]
    unsigned long long* geo = sh;
    unsigned long long* fxy = sh + K;
    const int tid = threadIdx.x;

    if (blockIdx.x == 0 && tid < 192) statsBuf[tid] = 0.f;

    for (int i = tid; i < K; i += TPB) { geo[i] = 0ull; fxy[i] = 0ull; }
    __syncthreads();

    const int P = H * W;
    const int b = blockIdx.x / chunks;
    const int chunk = blockIdx.x - b * chunks;
    const int chunkP = P / chunks;
    const size_t base = (size_t)b * P + (size_t)chunk * chunkP;
    const int4*   l4p  = (const int4*)(labels + base);
    const float4* fx4p = (const float4*)(fx + base);
    const float4* fy4p = (const float4*)(fy + base);
    const int nvec = chunkP >> 2;

    for (int v = tid; v < nvec; v += TPB) {
        int4   l4 = l4p[v];
        float4 f4 = fx4p[v];
        float4 g4 = fy4p[v];
        int p0 = chunk * chunkP + (v << 2);
        int   ls[4] = {l4.x, l4.y, l4.z, l4.w};
        float fs[4] = {f4.x, f4.y, f4.z, f4.w};
        float gs[4] = {g4.x, g4.y, g4.z, g4.w};
        #pragma unroll
        for (int s = 0; s < 4; ++s) {
            int p = p0 + s;
            int i, j;
            if (wlog >= 0) { i = p >> wlog; j = p & (W - 1); }
            else           { i = p / W;     j = p - i * W; }
            unsigned long long gadd = ((unsigned long long)i << 40)
                                    | ((unsigned long long)j << 16) | 1ull;
            int qx = __float2int_rn(fminf(fmaxf(fs[s], -15.f), 15.f) * FSCALE) + FBIAS;
            int qy = __float2int_rn(fminf(fmaxf(gs[s], -15.f), 15.f) * FSCALE) + FBIAS;
            unsigned long long fadd = ((unsigned long long)(unsigned int)qx << 32)
                                    | (unsigned long long)(unsigned int)qy;
            atomicAdd(&geo[ls[s]], gadd);
            atomicAdd(&fxy[ls[s]], fadd);
        }
    }
    __syncthreads();

    const float sx = 2.f / (float)(H - 1);           // xx varies along dim 2 (i)
    const float sy = 2.f / (float)(W - 1);           // yy varies along dim 3 (j)
    float* outp = partial + (size_t)blockIdx.x * K * 5;
    for (int k = tid; k < K; k += TPB) {
        unsigned long long g = geo[k];
        unsigned long long ff = fxy[k];
        unsigned int ci = (unsigned int)(g & 0xFFFFull);
        float cnt = (float)ci;
        float sj  = (float)(unsigned int)((g >> 16) & 0xFFFFFFull);
        float si  = (float)(unsigned int)(g >> 40);
        long long cbias = (long long)ci << 19;
        float* p = outp + k * 5;
        p[0] = (float)((long long)(ff >> 32) - cbias) * INV_FSCALE;          // sum fx
        p[1] = (float)((long long)(ff & 0xFFFFFFFFull) - cbias) * INV_FSCALE; // sum fy
        p[2] = sx * si - cnt;                        // sum xx
        p[3] = sy * sj - cnt;                        // sum yy
        p[4] = cnt;                                  // count
    }
}

// -------------------- fusedA: coalesced reduce + mean + layer1 + bn1 stats --------
// (byte-identical to the round-3 passing version)
__global__ void fusedA_kernel(const float* __restrict__ partial,
                              const int* __restrict__ frame_idx,
                              const int* __restrict__ n_frames_p,
                              const float* __restrict__ conv_w,
                              const float* __restrict__ conv_b,
                              float* __restrict__ h1,
                              float* __restrict__ statsBuf,
                              int K, int N, int chunks) {
    __shared__ float red[320];
    __shared__ float feat[320];
    __shared__ float cw[320];
    __shared__ float cb[64];
    const int tid = threadIdx.x;
    for (int i = tid; i < 320; i += TPB) cw[i] = conv_w[i];
    if (tid < 64) cb[tid] = conv_b[tid];

    const int t0 = blockIdx.x * 64;
    const int b  = t0 / K;                            // 64 | K, so one batch per block
    const int k0 = t0 - b * K;

    float acc0 = 0.f, acc1 = 0.f;
    const float* pb = partial + ((size_t)b * chunks * K + k0) * 5;
    for (int ch = 0; ch < chunks; ++ch) {
        const float* pc = pb + (size_t)ch * K * 5;
        acc0 += pc[tid];
        if (tid < 64) acc1 += pc[256 + tid];
    }
    red[tid] = acc0;
    if (tid < 64) red[256 + tid] = acc1;
    __syncthreads();

    const int g  = tid >> 6;
    const int tt = tid & 63;
    const int t  = t0 + tt;
    const bool valid = t < N;
    if (g == 0) {
        const float* r = red + tt * 5;
        float inv = 1.f / fmaxf(r[4], 1.f);
        float invnf = 1.f / (float)(n_frames_p[0] - 1);
        feat[tt * 5 + 0] = valid ? (float)frame_idx[b] * invnf : 0.f;
        feat[tt * 5 + 1] = r[0] * inv;
        feat[tt * 5 + 2] = r[1] * inv;
        feat[tt * 5 + 3] = r[2] * inv;
        feat[tt * 5 + 4] = r[3] * inv;
    }
    __syncthreads();

    const float x0 = feat[tt * 5 + 0], x1 = feat[tt * 5 + 1],
                x2 = feat[tt * 5 + 2], x3 = feat[tt * 5 + 3],
                x4 = feat[tt * 5 + 4];
    float hs[16];
    const int c0 = g * 16;
    #pragma unroll
    for (int j = 0; j < 16; ++j) {
        int c = c0 + j;
        const float* w = cw + c * 5;
        float h = cb[c] + w[0]*x0 + w[1]*x1 + w[2]*x2 + w[3]*x3 + w[4]*x4;
        hs[j] = valid ? h : 0.f;
        if (valid) h1[(size_t)c * N + t] = h;
    }

    float mySum = 0.f, mySq = 0.f;
    #pragma unroll
    for (int j = 0; j < 16; ++j) {
        float s = hs[j];
        float q = hs[j] * hs[j];
        #pragma unroll
        for (int m = 1; m < 64; m <<= 1) {
            s += __shfl_xor(s, m, 64);
            q += __shfl_xor(q, m, 64);
        }
        if (tt == j) { mySum = s; mySq = q; }
    }
    if (tt < 16) {
        atomicAdd(statsBuf + c0 + tt, mySum);
        atomicAdd(statsBuf + 64 + c0 + tt, mySq);
    }
}

// -------------------- fusedB: fold bn1 + relu + layer2 + bn2 stats ----------------
// (byte-identical to the round-3 passing version)
__global__ void fusedB_kernel(const float* __restrict__ h1,
                              const float* __restrict__ bn1_g,
                              const float* __restrict__ bn1_b,
                              const float* __restrict__ lin_w,
                              const float* __restrict__ lin_b,
                              float* __restrict__ h2,
                              float* __restrict__ statsBuf,
                              int N) {
    __shared__ float w[2048];
    __shared__ float sc[64], sh[64], lb[32];
    const int tid = threadIdx.x;
    for (int i = tid; i < 2048; i += TPB) w[i] = lin_w[i];
    if (tid < 64) {
        float invN = 1.f / (float)N;
        float mean = statsBuf[tid] * invN;
        float var  = statsBuf[64 + tid] * invN - mean * mean;
        float s = bn1_g[tid] * rsqrtf(var + 1e-5f);
        sc[tid] = s;
        sh[tid] = bn1_b[tid] - mean * s;
    }
    if (tid < 32) lb[tid] = lin_b[tid];
    __syncthreads();

    const int g  = tid >> 6;
    const int tt = tid & 63;
    const int t  = blockIdx.x * 64 + tt;
    const bool valid = t < N;
    float y[64];
    #pragma unroll
    for (int c = 0; c < 64; ++c)
        y[c] = valid ? fmaxf(h1[(size_t)c * N + t] * sc[c] + sh[c], 0.f) : 0.f;

    float hs[8];
    const int o0 = g * 8;
    #pragma unroll
    for (int j = 0; j < 8; ++j) {
        int o = o0 + j;
        const float* wo = w + o * 64;
        float acc = lb[o];
        #pragma unroll
        for (int c = 0; c < 64; ++c) acc += wo[c] * y[c];
        hs[j] = valid ? acc : 0.f;
        if (valid) h2[(size_t)o * N + t] = acc;
    }

    float mySum = 0.f, mySq = 0.f;
    #pragma unroll
    for (int j = 0; j < 8; ++j) {
        float s = hs[j];
        float q = hs[j] * hs[j];
        #pragma unroll
        for (int m = 1; m < 64; m <<= 1) {
            s += __shfl_xor(s, m, 64);
            q += __shfl_xor(q, m, 64);
        }
        if (tt == j) { mySum = s; mySq = q; }
    }
    if (tt < 8) {
        atomicAdd(statsBuf + 128 + o0 + tt, mySum);
        atomicAdd(statsBuf + 160 + o0 + tt, mySq);
    }
}

// -------------------- final: fold bn2 + relu + L2 normalize -----------------------
// (byte-identical to the round-3 passing version)
__global__ void final_kernel(const float* __restrict__ h2,
                             const float* __restrict__ bn2_g,
                             const float* __restrict__ bn2_b,
                             const float* __restrict__ statsBuf,
                             float* __restrict__ out, int N) {
    __shared__ float sc[32], sh[32];
    __shared__ float vtile[32 * 65];
    __shared__ float ssqp[4 * 64];
    __shared__ float linv[64];
    const int tid = threadIdx.x;
    if (tid < 32) {
        float invN = 1.f / (float)N;
        float mean = statsBuf[128 + tid] * invN;
        float var  = statsBuf[160 + tid] * invN - mean * mean;
        float s = bn2_g[tid] * rsqrtf(var + 1e-5f);
        sc[tid] = s;
        sh[tid] = bn2_b[tid] - mean * s;
    }
    __syncthreads();

    const int g  = tid >> 6;
    const int tt = tid & 63;
    const int t  = blockIdx.x * 64 + tt;
    const bool valid = t < N;
    const int o0 = g * 8;
    float ss = 0.f;
    #pragma unroll
    for (int j = 0; j < 8; ++j) {
        int o = o0 + j;
        float v = valid ? fmaxf(h2[(size_t)o * N + t] * sc[o] + sh[o], 0.f) : 0.f;
        vtile[o * 65 + tt] = v;
        ss += v * v;
    }
    ssqp[g * 64 + tt] = ss;
    __syncthreads();
    if (g == 0) {
        float tot = ssqp[tt] + ssqp[64 + tt] + ssqp[128 + tt] + ssqp[192 + tt];
        linv[tt] = 1.f / fmaxf(sqrtf(tot), 1e-8f);
    }
    __syncthreads();

    const int nq = min(512, (N - blockIdx.x * 64) * 8);   // float4s this block owns
    float4* o4 = (float4*)(out + (size_t)blockIdx.x * 64 * 32);
    for (int q = tid; q < nq; q += TPB) {
        int tk = q >> 3;
        int oo = (q & 7) * 4;
        float iv = linv[tk];
        o4[q] = make_float4(vtile[(oo + 0) * 65 + tk] * iv,
                            vtile[(oo + 1) * 65 + tk] * iv,
                            vtile[(oo + 2) * 65 + tk] * iv,
                            vtile[(oo + 3) * 65 + tk] * iv);
    }
}

extern "C" void kernel_launch(void* const* d_in, const int* in_sizes, int n_in,
                              void* d_out, int out_size, void* d_ws, size_t ws_size,
                              hipStream_t stream) {
    const int*   labels     = (const int*)d_in[0];
    const float* fx         = (const float*)d_in[1];
    const float* fy         = (const float*)d_in[2];
    const int*   frame_idx  = (const int*)d_in[3];
    const int*   n_frames_p = (const int*)d_in[4];
    // d_in[5] = n_labels (derived from out_size instead)
    const float* conv_w = (const float*)d_in[6];
    const float* conv_b = (const float*)d_in[7];
    const float* bn1_g  = (const float*)d_in[8];
    const float* bn1_b  = (const float*)d_in[9];
    const float* lin_w  = (const float*)d_in[10];
    const float* lin_b  = (const float*)d_in[11];
    const float* bn2_g  = (const float*)d_in[12];
    const float* bn2_b  = (const float*)d_in[13];
    float* out = (float*)d_out;

    const int B = in_sizes[3];                       // 16
    const int P = in_sizes[0] / B;                   // 262144
    const int W = (int)(sqrt((double)P) + 0.5);      // 512 (square image)
    const int H = P / W;
    const int K = out_size / (B * 32);               // 1024
    const int N = B * K;                             // 16384

    int wlog = -1;
    if ((W & (W - 1)) == 0) { wlog = 0; while ((1 << wlog) < W) ++wlog; }

    // workspace layout (floats): h1[64*N] | h2[32*N] | statsBuf[256] | partial[B*chunks*K*5]
    float* h1       = (float*)d_ws;
    float* h2       = h1 + (size_t)64 * N;
    float* statsBuf = h2 + (size_t)32 * N;
    float* partial  = statsBuf + 256;
    const size_t fixed_bytes = ((size_t)96 * N + 256) * sizeof(float);

    int chunks = 64;
    while (chunks > 1 &&
           ((size_t)B * chunks * K * 5 * sizeof(float) + fixed_bytes > ws_size ||
            (P % (chunks * 4)) != 0))
        chunks >>= 1;
    while (P / chunks > 4096) chunks <<= 1;          // u64 fxy packing bound (2^15 scale)

    pool_kernel<<<B * chunks, TPB, (size_t)K * 16, stream>>>(
        labels, fx, fy, partial, statsBuf, K, H, W, wlog, chunks);
    fusedA_kernel<<<(N + 63) / 64, TPB, 0, stream>>>(
        partial, frame_idx, n_frames_p, conv_w, conv_b, h1, statsBuf, K, N, chunks);
    fusedB_kernel<<<(N + 63) / 64, TPB, 0, stream>>>(
        h1, bn1_g, bn1_b, lin_w, lin_b, h2, statsBuf, N);
    final_kernel<<<(N + 63) / 64, TPB, 0, stream>>>(
        h2, bn2_g, bn2_b, statsBuf, out, N);
}

// Round 8
// 169.794 us; speedup vs baseline: 2.1740x; 1.0404x over previous
//
#include <hip/hip_runtime.h>
#include <math.h>

#define TPB 256
#define FSCALE 32768.0f            // 2^15 fixed-point for fx/fy
#define INV_FSCALE (1.0f / 32768.0f)
#define FBIAS (1 << 19)            // per-add bias keeps packed fields positive

// ctrl (floats): [0:64) bn1 sum, [64:128) bn1 sumsq, [128:160) bn2 sum,
// [160:192) bn2 sumsq, int counters at [192] and [208] (separate cachelines).

// -------------------- pool: LDS int bins, 2 u64 atomics/pixel (round-7 proven) ----
__global__ void pool_kernel(const int* __restrict__ labels,
                            const float* __restrict__ fx,
                            const float* __restrict__ fy,
                            float* __restrict__ partial,
                            float* __restrict__ ctrl,
                            int K, int H, int W, int wlog, int chunks) {
    extern __shared__ unsigned long long sh[];   // geo[K] | fxy[K]
    unsigned long long* geo = sh;
    unsigned long long* fxy = sh + K;
    const int tid = threadIdx.x;

    if (blockIdx.x == 0 && tid < 224) ctrl[tid] = 0.f;   // stats + barrier counters

    for (int i = tid; i < K; i += TPB) { geo[i] = 0ull; fxy[i] = 0ull; }
    __syncthreads();

    const int P = H * W;
    const int b = blockIdx.x / chunks;
    const int chunk = blockIdx.x - b * chunks;
    const int chunkP = P / chunks;
    const size_t base = (size_t)b * P + (size_t)chunk * chunkP;
    const int4*   l4p  = (const int4*)(labels + base);
    const float4* fx4p = (const float4*)(fx + base);
    const float4* fy4p = (const float4*)(fy + base);
    const int nvec = chunkP >> 2;

    for (int v = tid; v < nvec; v += TPB) {
        int4   l4 = l4p[v];
        float4 f4 = fx4p[v];
        float4 g4 = fy4p[v];
        int p0 = chunk * chunkP + (v << 2);
        int   ls[4] = {l4.x, l4.y, l4.z, l4.w};
        float fs[4] = {f4.x, f4.y, f4.z, f4.w};
        float gs[4] = {g4.x, g4.y, g4.z, g4.w};
        #pragma unroll
        for (int s = 0; s < 4; ++s) {
            int p = p0 + s;
            int i, j;
            if (wlog >= 0) { i = p >> wlog; j = p & (W - 1); }
            else           { i = p / W;     j = p - i * W; }
            unsigned long long gadd = ((unsigned long long)i << 40)
                                    | ((unsigned long long)j << 16) | 1ull;
            int qx = __float2int_rn(fminf(fmaxf(fs[s], -15.f), 15.f) * FSCALE) + FBIAS;
            int qy = __float2int_rn(fminf(fmaxf(gs[s], -15.f), 15.f) * FSCALE) + FBIAS;
            unsigned long long fadd = ((unsigned long long)(unsigned int)qx << 32)
                                    | (unsigned long long)(unsigned int)qy;
            atomicAdd(&geo[ls[s]], gadd);
            atomicAdd(&fxy[ls[s]], fadd);
        }
    }
    __syncthreads();

    const float sx = 2.f / (float)(H - 1);           // xx varies along dim 2 (i)
    const float sy = 2.f / (float)(W - 1);           // yy varies along dim 3 (j)
    float* outp = partial + (size_t)blockIdx.x * K * 5;
    for (int k = tid; k < K; k += TPB) {
        unsigned long long g = geo[k];
        unsigned long long ff = fxy[k];
        unsigned int ci = (unsigned int)(g & 0xFFFFull);
        float cnt = (float)ci;
        float sj  = (float)(unsigned int)((g >> 16) & 0xFFFFFFull);
        float si  = (float)(unsigned int)(g >> 40);
        long long cbias = (long long)ci << 19;
        float* p = outp + k * 5;
        p[0] = (float)((long long)(ff >> 32) - cbias) * INV_FSCALE;           // sum fx
        p[1] = (float)((long long)(ff & 0xFFFFFFFFull) - cbias) * INV_FSCALE; // sum fy
        p[2] = sx * si - cnt;                        // sum xx
        p[3] = sy * sj - cnt;                        // sum yy
        p[4] = cnt;                                  // count
    }
}

// -------------------- fence-free grid barrier ------------------------------------
// All cross-block data flows through device-scope atomics (coherence point), so
// no __threadfence (i.e., no cache-wide wbl2/inv storms — the round-4/5 killer).
__device__ __forceinline__ void grid_sync(int* cnt, int nblk) {
    __syncthreads();                     // drains each wave's vmcnt (stats atomics done)
    if (threadIdx.x == 0) {
        __hip_atomic_fetch_add(cnt, 1, __ATOMIC_RELEASE, __HIP_MEMORY_SCOPE_AGENT);
        while (__hip_atomic_load(cnt, __ATOMIC_ACQUIRE, __HIP_MEMORY_SCOPE_AGENT) < nblk)
            __builtin_amdgcn_s_sleep(16);            // ~1k cycles between polls
    }
    __syncthreads();
}

// -------------------- K2: reduce+layer1 | bn1+layer2 | bn2+normalize -------------
// 256 blocks x 256 threads; block owns 64 tokens; h1/h2 live in LDS only.
__global__ __launch_bounds__(TPB)
void fused234_kernel(const float* __restrict__ partial,
                     const int* __restrict__ frame_idx,
                     const int* __restrict__ n_frames_p,
                     const float* __restrict__ conv_w,
                     const float* __restrict__ conv_b,
                     const float* __restrict__ bn1_g,
                     const float* __restrict__ bn1_b,
                     const float* __restrict__ lin_w,
                     const float* __restrict__ lin_b,
                     const float* __restrict__ bn2_g,
                     const float* __restrict__ bn2_b,
                     float* __restrict__ ctrl,
                     float* __restrict__ out,
                     int K, int N, int chunks) {
    __shared__ float red[320], feat[320], cw[320], cb[64];
    __shared__ float h1t[64 * 64];                   // [c][tt]
    __shared__ float w2[2048], lb[32];
    __shared__ float sc1[64], sh1[64], sc2[32], sh2[32];
    __shared__ float h2t[32 * 65];                   // [o][tt], padded
    __shared__ float ssqp[4 * 64], linv[64];

    const int tid = threadIdx.x;
    const int nblk = gridDim.x;
    int* cnt0 = (int*)(ctrl + 192);
    int* cnt1 = (int*)(ctrl + 208);

    // stage weights (overlaps phase A loads)
    for (int i = tid; i < 320; i += TPB) cw[i] = conv_w[i];
    if (tid < 64) cb[tid] = conv_b[tid];
    for (int i = tid; i < 2048; i += TPB) w2[i] = lin_w[i];
    if (tid < 32) lb[tid] = lin_b[tid];

    // ---------- phase A: reduce slabs + mean + layer1 (LDS) + bn1 stats ----------
    const int t0 = blockIdx.x * 64;
    const int b  = t0 / K;                           // 64 | K -> one batch per block
    const int k0 = t0 - b * K;

    float acc0 = 0.f, acc1 = 0.f;
    const float* pb = partial + ((size_t)b * chunks * K + k0) * 5;
    for (int ch = 0; ch < chunks; ++ch) {
        const float* pc = pb + (size_t)ch * K * 5;
        acc0 += pc[tid];
        if (tid < 64) acc1 += pc[256 + tid];
    }
    red[tid] = acc0;
    if (tid < 64) red[256 + tid] = acc1;
    __syncthreads();

    const int g  = tid >> 6;
    const int tt = tid & 63;
    const int t  = t0 + tt;
    const bool valid = t < N;
    if (g == 0) {
        const float* r = red + tt * 5;
        float inv = 1.f / fmaxf(r[4], 1.f);
        float invnf = 1.f / (float)(n_frames_p[0] - 1);
        feat[tt * 5 + 0] = valid ? (float)frame_idx[b] * invnf : 0.f;
        feat[tt * 5 + 1] = r[0] * inv;
        feat[tt * 5 + 2] = r[1] * inv;
        feat[tt * 5 + 3] = r[2] * inv;
        feat[tt * 5 + 4] = r[3] * inv;
    }
    __syncthreads();

    {
        const float x0 = feat[tt * 5 + 0], x1 = feat[tt * 5 + 1],
                    x2 = feat[tt * 5 + 2], x3 = feat[tt * 5 + 3],
                    x4 = feat[tt * 5 + 4];
        float hs[16];
        const int c0 = g * 16;
        #pragma unroll
        for (int j = 0; j < 16; ++j) {
            int c = c0 + j;
            const float* w = cw + c * 5;
            float h = cb[c] + w[0]*x0 + w[1]*x1 + w[2]*x2 + w[3]*x3 + w[4]*x4;
            h1t[c * 64 + tt] = h;
            hs[j] = valid ? h : 0.f;
        }
        float mySum = 0.f, mySq = 0.f;
        #pragma unroll
        for (int j = 0; j < 16; ++j) {
            float s = hs[j];
            float q = hs[j] * hs[j];
            #pragma unroll
            for (int m = 1; m < 64; m <<= 1) {
                s += __shfl_xor(s, m, 64);
                q += __shfl_xor(q, m, 64);
            }
            if (tt == j) { mySum = s; mySq = q; }
        }
        if (tt < 16) {
            atomicAdd(ctrl + c0 + tt, mySum);
            atomicAdd(ctrl + 64 + c0 + tt, mySq);
        }
    }

    grid_sync(cnt0, nblk);

    // ---------- phase B: fold bn1 + relu + layer2 (LDS) + bn2 stats --------------
    if (tid < 64) {
        float invN = 1.f / (float)N;
        float su = __hip_atomic_load(ctrl + tid,      __ATOMIC_RELAXED, __HIP_MEMORY_SCOPE_AGENT);
        float sq = __hip_atomic_load(ctrl + 64 + tid, __ATOMIC_RELAXED, __HIP_MEMORY_SCOPE_AGENT);
        float mean = su * invN;
        float var  = sq * invN - mean * mean;
        float s = bn1_g[tid] * rsqrtf(var + 1e-5f);
        sc1[tid] = s;
        sh1[tid] = bn1_b[tid] - mean * s;
    }
    __syncthreads();

    float y[64];
    #pragma unroll
    for (int c = 0; c < 64; ++c)
        y[c] = fmaxf(h1t[c * 64 + tt] * sc1[c] + sh1[c], 0.f);

    {
        float hs[8];
        const int o0 = g * 8;
        #pragma unroll
        for (int j = 0; j < 8; ++j) {
            int o = o0 + j;
            const float* wo = w2 + o * 64;
            float acc = lb[o];
            #pragma unroll
            for (int c = 0; c < 64; ++c) acc += wo[c] * y[c];
            h2t[o * 65 + tt] = acc;
            hs[j] = valid ? acc : 0.f;
        }
        float mySum = 0.f, mySq = 0.f;
        #pragma unroll
        for (int j = 0; j < 8; ++j) {
            float s = hs[j];
            float q = hs[j] * hs[j];
            #pragma unroll
            for (int m = 1; m < 64; m <<= 1) {
                s += __shfl_xor(s, m, 64);
                q += __shfl_xor(q, m, 64);
            }
            if (tt == j) { mySum = s; mySq = q; }
        }
        if (tt < 8) {
            atomicAdd(ctrl + 128 + o0 + tt, mySum);
            atomicAdd(ctrl + 160 + o0 + tt, mySq);
        }
    }

    grid_sync(cnt1, nblk);

    // ---------- phase C: fold bn2 + relu + L2 normalize + store ------------------
    if (tid < 32) {
        float invN = 1.f / (float)N;
        float su = __hip_atomic_load(ctrl + 128 + tid, __ATOMIC_RELAXED, __HIP_MEMORY_SCOPE_AGENT);
        float sq = __hip_atomic_load(ctrl + 160 + tid, __ATOMIC_RELAXED, __HIP_MEMORY_SCOPE_AGENT);
        float mean = su * invN;
        float var  = sq * invN - mean * mean;
        float s = bn2_g[tid] * rsqrtf(var + 1e-5f);
        sc2[tid] = s;
        sh2[tid] = bn2_b[tid] - mean * s;
    }
    __syncthreads();

    {
        const int o0 = g * 8;
        float ss = 0.f;
        #pragma unroll
        for (int j = 0; j < 8; ++j) {
            int o = o0 + j;
            float v = fmaxf(h2t[o * 65 + tt] * sc2[o] + sh2[o], 0.f);
            h2t[o * 65 + tt] = v;
            ss += v * v;
        }
        ssqp[g * 64 + tt] = ss;
    }
    __syncthreads();
    if (g == 0) {
        float tot = ssqp[tt] + ssqp[64 + tt] + ssqp[128 + tt] + ssqp[192 + tt];
        linv[tt] = 1.f / fmaxf(sqrtf(tot), 1e-8f);
    }
    __syncthreads();

    const int nq = min(512, (N - t0) * 8);           // float4s this block owns
    float4* o4 = (float4*)(out + (size_t)t0 * 32);
    for (int q = tid; q < nq; q += TPB) {
        int tk = q >> 3;
        int oo = (q & 7) * 4;
        float iv = linv[tk];
        o4[q] = make_float4(h2t[(oo + 0) * 65 + tk] * iv,
                            h2t[(oo + 1) * 65 + tk] * iv,
                            h2t[(oo + 2) * 65 + tk] * iv,
                            h2t[(oo + 3) * 65 + tk] * iv);
    }
}

extern "C" void kernel_launch(void* const* d_in, const int* in_sizes, int n_in,
                              void* d_out, int out_size, void* d_ws, size_t ws_size,
                              hipStream_t stream) {
    const int*   labels     = (const int*)d_in[0];
    const float* fx         = (const float*)d_in[1];
    const float* fy         = (const float*)d_in[2];
    const int*   frame_idx  = (const int*)d_in[3];
    const int*   n_frames_p = (const int*)d_in[4];
    // d_in[5] = n_labels (derived from out_size instead)
    const float* conv_w = (const float*)d_in[6];
    const float* conv_b = (const float*)d_in[7];
    const float* bn1_g  = (const float*)d_in[8];
    const float* bn1_b  = (const float*)d_in[9];
    const float* lin_w  = (const float*)d_in[10];
    const float* lin_b  = (const float*)d_in[11];
    const float* bn2_g  = (const float*)d_in[12];
    const float* bn2_b  = (const float*)d_in[13];
    float* out = (float*)d_out;

    const int B = in_sizes[3];                       // 16
    const int P = in_sizes[0] / B;                   // 262144
    const int W = (int)(sqrt((double)P) + 0.5);      // 512 (square image)
    const int H = P / W;
    const int K = out_size / (B * 32);               // 1024
    const int N = B * K;                             // 16384

    int wlog = -1;
    if ((W & (W - 1)) == 0) { wlog = 0; while ((1 << wlog) < W) ++wlog; }

    // workspace layout (floats): ctrl[256] | partial[B*chunks*K*5]
    float* ctrl    = (float*)d_ws;
    float* partial = ctrl + 256;

    int chunks = 64;
    while (chunks > 1 &&
           ((size_t)B * chunks * K * 5 * sizeof(float) + 1024 > ws_size ||
            (P % (chunks * 4)) != 0))
        chunks >>= 1;
    while (P / chunks > 4096) chunks <<= 1;          // u64 fxy packing bound (2^15 scale)

    const int nblk = (N + 63) / 64;                  // 256 blocks; 38 KB LDS -> 4/CU capacity

    pool_kernel<<<B * chunks, TPB, (size_t)K * 16, stream>>>(
        labels, fx, fy, partial, ctrl, K, H, W, wlog, chunks);
    fused234_kernel<<<nblk, TPB, 0, stream>>>(
        partial, frame_idx, n_frames_p, conv_w, conv_b, bn1_g, bn1_b,
        lin_w, lin_b, bn2_g, bn2_b, ctrl, out, K, N, chunks);
}